// Round 1
// baseline (253.240 us; speedup 1.0000x reference)
//
#include <hip/hip_runtime.h>
#include <math.h>

// 2D IDCT 4096x4096 via Makhoul half-size complex IFFT per row + transpose.
// out = transpose(idct_rows(transpose(idct_rows(x))))

#define NN 4096
#define HH 2048     // half size: packed complex IFFT length
#define TT 256      // threads per block

// ---------------- twiddle init: tw[k] = exp(+2*pi*i*k/4096), k < 2048 ------
__global__ void tw_init_kernel(float2* __restrict__ tw) {
    int t = threadIdx.x;
    for (int i = 0; i < HH / TT; ++i) {
        int k = t + i * TT;
        double a = (2.0 * M_PI * (double)k) / (double)NN;
        tw[k] = make_float2((float)cos(a), (float)sin(a));
    }
}

// ---------------- row IDCT kernel -----------------------------------------
// One block per row. Builds Z (packed spectrum), 11-stage Stockham IFFT in
// LDS, de-interleaves v -> out per the reference's even/odd mapping.
__global__ __launch_bounds__(TT) void idct_rows_kernel(
    const float* __restrict__ in, const float2* __restrict__ expk,
    const float2* __restrict__ tw, float* __restrict__ out) {
    __shared__ float twr[HH], twi[HH];
    __shared__ float ar[HH], ai[HH], br[HH], bi[HH];

    const int t = threadIdx.x;
    const int row = blockIdx.x;
    const float* __restrict__ xr = in + (size_t)row * NN;
    float* __restrict__ orow = out + (size_t)row * NN;

    // stage twiddles -> LDS (also used per-thread in Z build via register w)
    const float sc = 1.0f / 4096.0f;  // (1/2 from A,B defs) * (1/2048 IFFT)
    for (int i = 0; i < HH / TT; ++i) {
        int k = t + i * TT;
        float2 w = tw[k];
        twr[k] = w.x; twi[k] = w.y;

        // --- build Z[k] ---
        // V[k]    = 0.5*(X[k]     - i*X[N-k])  * expk[k]      (X[N-0] -> 0)
        // V[k+H]  = 0.5*(X[k+H]   - i*X[H-k])  * expk[k+H]
        // Z[k]    = (V[k]+V[k+H])/2 + i*w*(V[k]-V[k+H])/2 ,  w = e^{2pi i k/N}
        float xa = xr[k];
        float xb = (k == 0) ? 0.0f : xr[NN - k];
        float2 e1 = expk[k];
        float var_ = 0.5f * (xa * e1.x + xb * e1.y);
        float vai_ = 0.5f * (xa * e1.y - xb * e1.x);
        float xc = xr[k + HH];
        float xd = xr[HH - k];
        float2 e2 = expk[k + HH];
        float vbr_ = 0.5f * (xc * e2.x + xd * e2.y);
        float vbi_ = 0.5f * (xc * e2.y - xd * e2.x);
        float sr = var_ + vbr_, si = vai_ + vbi_;
        float dr = var_ - vbr_, di = vai_ - vbi_;
        // i*w*(dr+i*di) = -(w.x*di + w.y*dr) + i*(w.x*dr - w.y*di)
        ar[k] = (sr - (w.x * di + w.y * dr)) * sc;
        ai[k] = (si + (w.x * dr - w.y * di)) * sc;
    }
    __syncthreads();

    // --- Stockham radix-2 IFFT (sign +), 2048 = 2^11, auto-sorting ---
    float* sr_ = ar; float* si_ = ai; float* dr_ = br; float* di_ = bi;
    for (int s = 0; s < 11; ++s) {
        const int m = 1 << s;
        for (int i = 0; i < (HH / 2) / TT; ++i) {  // 4 butterflies/thread
            int b = t + i * TT;
            int j = b >> s;
            int jm = j << s;          // j*m
            int o0 = b + jm;          // k + 2*j*m
            float c0r = sr_[b],        c0i = si_[b];
            float c1r = sr_[b + 1024], c1i = si_[b + 1024];  // l*m == 1024
            float sumr = c0r + c1r, sumi = c0i + c1i;
            float difr = c0r - c1r, difi = c0i - c1i;
            int wix = j << (s + 1);   // j * 2048/l
            float wr = twr[wix], wi = twi[wix];
            dr_[o0] = sumr;
            di_[o0] = sumi;
            dr_[o0 + m] = wr * difr - wi * difi;
            di_[o0 + m] = wr * difi + wi * difr;
        }
        __syncthreads();
        float* tmp;
        tmp = sr_; sr_ = dr_; dr_ = tmp;
        tmp = si_; si_ = di_; di_ = tmp;
    }
    // result z[m] now in sr_/si_ : v[2m] = Re z[m], v[2m+1] = Im z[m]

    // --- de-interleave: out[2m] = v[m]; out[2m+1] = v[N-1-m] ---
    for (int i = 0; i < NN / TT; ++i) {
        int q = t + i * TT;
        int vidx = (q & 1) ? (NN - 1 - ((q - 1) >> 1)) : (q >> 1);
        float val = (vidx & 1) ? si_[vidx >> 1] : sr_[vidx >> 1];
        orow[q] = val;
    }
}

// ---------------- transpose (32x32 LDS tiles, padded) ---------------------
__global__ __launch_bounds__(256) void transpose_kernel(
    const float* __restrict__ in, float* __restrict__ out) {
    __shared__ float tile[32][33];
    int bx = blockIdx.x, by = blockIdx.y;
    int tx = threadIdx.x;  // 0..31
    int ty = threadIdx.y;  // 0..7
    int x = bx * 32 + tx;
    int y = by * 32 + ty;
    for (int j = 0; j < 32; j += 8)
        tile[ty + j][tx] = in[(size_t)(y + j) * NN + x];
    __syncthreads();
    int x2 = by * 32 + tx;
    int y2 = bx * 32 + ty;
    for (int j = 0; j < 32; j += 8)
        out[(size_t)(y2 + j) * NN + x2] = tile[tx][ty + j];
}

extern "C" void kernel_launch(void* const* d_in, const int* in_sizes, int n_in,
                              void* d_out, int out_size, void* d_ws, size_t ws_size,
                              hipStream_t stream) {
    const float* x      = (const float*)d_in[0];
    const float2* expkM = (const float2*)d_in[1];
    const float2* expkN = (const float2*)d_in[2];
    float* out = (float*)d_out;

    float2* tw = (float2*)d_ws;                           // 16 KB
    float* A   = (float*)((char*)d_ws + 65536);           // 64 MB scratch

    tw_init_kernel<<<1, TT, 0, stream>>>(tw);

    // pass 1: rows of x -> A ; transpose A -> out
    idct_rows_kernel<<<NN, TT, 0, stream>>>(x, expkN, tw, A);
    {
        dim3 g(NN / 32, NN / 32), b(32, 8);
        transpose_kernel<<<g, b, 0, stream>>>(A, out);
    }
    // pass 2: rows of out (= y^T) -> A ; transpose A -> out (final)
    idct_rows_kernel<<<NN, TT, 0, stream>>>(out, expkM, tw, A);
    {
        dim3 g(NN / 32, NN / 32), b(32, 8);
        transpose_kernel<<<g, b, 0, stream>>>(A, out);
    }
}

// Round 2
// 226.876 us; speedup vs baseline: 1.1162x; 1.1162x over previous
//
#include <hip/hip_runtime.h>
#include <math.h>

// 2D IDCT 4096x4096. Per row: Makhoul half-size packing -> 2048-pt complex
// IFFT via radix-8/8/8/4 register Stockham in LDS (skewed addressing),
// then de-interleave. Column pass via float4 swizzled transpose.

#define NN 4096
#define HH 2048
#define TT 256
#define PHYS(i) ((i) + ((i) >> 3))
#define C_SQ2 0.70710678118654752440f

// ---- twiddle init: tw4096[k]=e^{2pi i k/4096}, tw2048[k]=e^{2pi i k/2048} --
__global__ void tw_init_kernel(float2* __restrict__ tw4096,
                               float2* __restrict__ tw2048) {
    int t = threadIdx.x;
    for (int i = 0; i < HH / TT; ++i) {
        int k = t + i * TT;
        double a4 = (2.0 * M_PI * (double)k) / 4096.0;
        double a2 = (2.0 * M_PI * (double)k) / 2048.0;
        tw4096[k] = make_float2((float)cos(a4), (float)sin(a4));
        tw2048[k] = make_float2((float)cos(a2), (float)sin(a2));
    }
}

// radix-8 DFT with sign +:  t_q = sum_p a_p w8^{pq},  w8 = e^{+2pi i/8}
__device__ __forceinline__ void radix8(const float* ar, const float* ai,
                                       float* tr, float* ti) {
    // even DFT4 (a0,a2,a4,a6), w4 = i
    float s04r = ar[0] + ar[4], s04i = ai[0] + ai[4];
    float d04r = ar[0] - ar[4], d04i = ai[0] - ai[4];
    float s26r = ar[2] + ar[6], s26i = ai[2] + ai[6];
    float d26r = ar[2] - ar[6], d26i = ai[2] - ai[6];
    float E0r = s04r + s26r, E0i = s04i + s26i;
    float E1r = d04r - d26i, E1i = d04i + d26r;   // + i*(d26)
    float E2r = s04r - s26r, E2i = s04i - s26i;
    float E3r = d04r + d26i, E3i = d04i - d26r;   // - i*(d26)
    // odd DFT4 (a1,a3,a5,a7)
    float s15r = ar[1] + ar[5], s15i = ai[1] + ai[5];
    float d15r = ar[1] - ar[5], d15i = ai[1] - ai[5];
    float s37r = ar[3] + ar[7], s37i = ai[3] + ai[7];
    float d37r = ar[3] - ar[7], d37i = ai[3] - ai[7];
    float O0r = s15r + s37r, O0i = s15i + s37i;
    float O1r = d15r - d37i, O1i = d15i + d37r;
    float O2r = s15r - s37r, O2i = s15i - s37i;
    float O3r = d15r + d37i, O3i = d15i - d37r;
    // w8^1*(x+iy) = (c(x-y), c(x+y));  w8^2 = i;  w8^3*(x+iy) = (-c(x+y), c(x-y))
    float W1r = C_SQ2 * (O1r - O1i), W1i = C_SQ2 * (O1r + O1i);
    float W2r = -O2i, W2i = O2r;
    float W3r = -C_SQ2 * (O3r + O3i), W3i = C_SQ2 * (O3r - O3i);
    tr[0] = E0r + O0r; ti[0] = E0i + O0i;
    tr[4] = E0r - O0r; ti[4] = E0i - O0i;
    tr[1] = E1r + W1r; ti[1] = E1i + W1i;
    tr[5] = E1r - W1r; ti[5] = E1i - W1i;
    tr[2] = E2r + W2r; ti[2] = E2i + W2i;
    tr[6] = E2r - W2r; ti[6] = E2i - W2i;
    tr[3] = E3r + W3r; ti[3] = E3i + W3i;
    tr[7] = E3r - W3r; ti[7] = E3i - W3i;
}

__global__ __launch_bounds__(TT) void idct_rows_kernel(
    const float* __restrict__ in, const float2* __restrict__ expk,
    const float2* __restrict__ tw4096, const float2* __restrict__ tw2048,
    float* __restrict__ out) {
    __shared__ float b0r[2304], b0i[2304], b1r[2304], b1i[2304];
    const int t = threadIdx.x;
    const float* __restrict__ xr = in + (size_t)blockIdx.x * NN;
    float* __restrict__ orow = out + (size_t)blockIdx.x * NN;
    const float sc = 1.0f / 4096.0f;

    // ---- Z build in registers: Z[t + 256p], then stage A (m=1, R=8, j=t) ----
    float zr[8], zi[8];
#pragma unroll
    for (int p = 0; p < 8; ++p) {
        int k = t + TT * p;
        float xa = xr[k];
        float xb = xr[(NN - k) & (NN - 1)];
        xb = (k == 0) ? 0.0f : xb;
        float2 e1 = expk[k];
        float var_ = 0.5f * (xa * e1.x + xb * e1.y);
        float vai_ = 0.5f * (xa * e1.y - xb * e1.x);
        float xc = xr[k + HH];
        float xd = xr[HH - k];
        float2 e2 = expk[k + HH];
        float vbr_ = 0.5f * (xc * e2.x + xd * e2.y);
        float vbi_ = 0.5f * (xc * e2.y - xd * e2.x);
        float sr = var_ + vbr_, si = vai_ + vbi_;
        float dr = var_ - vbr_, di = vai_ - vbi_;
        float2 w = tw4096[k];
        zr[p] = (sr - (w.x * di + w.y * dr)) * sc;
        zi[p] = (si + (w.x * dr - w.y * di)) * sc;
    }
    {
        float tr[8], ti[8];
        radix8(zr, zi, tr, ti);
        int base = 9 * t;            // PHYS(8t+q) = 9t+q
        b0r[base] = tr[0]; b0i[base] = ti[0];
#pragma unroll
        for (int q = 1; q < 8; ++q) {
            float2 w = tw2048[(t * q) & (HH - 1)];
            b0r[base + q] = w.x * tr[q] - w.y * ti[q];
            b0i[base + q] = w.x * ti[q] + w.y * tr[q];
        }
    }
    __syncthreads();

    // ---- stage B: m=8, R=8, j=t>>3, k=t&7 ----
    {
        float ar[8], ai[8], tr[8], ti[8];
        int rb = PHYS(t);
#pragma unroll
        for (int p = 0; p < 8; ++p) { ar[p] = b0r[rb + 288 * p]; ai[p] = b0i[rb + 288 * p]; }
        radix8(ar, ai, tr, ti);
        int j = t >> 3;
        int wj = 8 * j;
        int base = 64 * j + t;       // PHYS(64j+8q+k) = base + 9q
        b1r[base] = tr[0]; b1i[base] = ti[0];
#pragma unroll
        for (int q = 1; q < 8; ++q) {
            float2 w = tw2048[(wj * q) & (HH - 1)];
            b1r[base + 9 * q] = w.x * tr[q] - w.y * ti[q];
            b1i[base + 9 * q] = w.x * ti[q] + w.y * tr[q];
        }
    }
    __syncthreads();

    // ---- stage C: m=64, R=8, j=t>>6, k=t&63 ----
    {
        float ar[8], ai[8], tr[8], ti[8];
        int rb = PHYS(t);
#pragma unroll
        for (int p = 0; p < 8; ++p) { ar[p] = b1r[rb + 288 * p]; ai[p] = b1i[rb + 288 * p]; }
        radix8(ar, ai, tr, ti);
        int j = t >> 6;
        int wj = 64 * j;
        int k = t & 63;
        int base = 576 * j + PHYS(k);  // + 72q
        b0r[base] = tr[0]; b0i[base] = ti[0];
#pragma unroll
        for (int q = 1; q < 8; ++q) {
            float2 w = tw2048[(wj * q) & (HH - 1)];
            b0r[base + 72 * q] = w.x * tr[q] - w.y * ti[q];
            b0i[base + 72 * q] = w.x * ti[q] + w.y * tr[q];
        }
    }
    __syncthreads();

    // ---- stage D: m=512, R=4, j=0, twiddles = 1; two butterflies ----
#pragma unroll
    for (int u = 0; u < 2; ++u) {
        int b = t + TT * u;
        int rb = PHYS(b);
        float a0r = b0r[rb], a0i = b0i[rb];
        float a1r = b0r[rb + 576], a1i = b0i[rb + 576];
        float a2r = b0r[rb + 1152], a2i = b0i[rb + 1152];
        float a3r = b0r[rb + 1728], a3i = b0i[rb + 1728];
        float s02r = a0r + a2r, s02i = a0i + a2i;
        float d02r = a0r - a2r, d02i = a0i - a2i;
        float s13r = a1r + a3r, s13i = a1i + a3i;
        float d13r = a1r - a3r, d13i = a1i - a3i;
        b1r[rb] = s02r + s13r;          b1i[rb] = s02i + s13i;
        b1r[rb + 576] = d02r - d13i;    b1i[rb + 576] = d02i + d13r;   // +i*d13
        b1r[rb + 1152] = s02r - s13r;   b1i[rb + 1152] = s02i - s13i;
        b1r[rb + 1728] = d02r + d13i;   b1i[rb + 1728] = d02i - d13r;  // -i*d13
    }
    __syncthreads();

    // ---- de-interleave: out[2p]=v[p], out[2p+1]=v[4095-p]; v[2m]=Re z[m], v[2m+1]=Im z[m]
#pragma unroll
    for (int i = 0; i < NN / TT; ++i) {
        int q = t + TT * i;
        int vidx = (q & 1) ? (NN - 1 - ((q - 1) >> 1)) : (q >> 1);
        int m_ = PHYS(vidx >> 1);
        float val = (vidx & 1) ? b1i[m_] : b1r[m_];
        orow[q] = val;
    }
}

// ---------------- transpose: 64x64 tiles, float4, XOR-swizzled LDS ----------
__global__ __launch_bounds__(256) void transpose_kernel(
    const float* __restrict__ in, float* __restrict__ out) {
    __shared__ float tile[64 * 64];
    int bx = blockIdx.x, by = blockIdx.y;
    int tx = threadIdx.x;  // 0..15
    int ty = threadIdx.y;  // 0..15
#pragma unroll
    for (int j = 0; j < 4; ++j) {
        int y = ty + 16 * j;
        float4 v = ((const float4*)(in + (size_t)(by * 64 + y) * NN + bx * 64))[tx];
        // tile[X][Y] = in[by*64+Y][bx*64+X], X = 4tx+c, swizzled at float4 gran
        int X0 = 4 * tx;
        tile[(X0 + 0) * 64 + ((((y >> 2) ^ ((X0 + 0) & 15)) << 2) | (y & 3))] = v.x;
        tile[(X0 + 1) * 64 + ((((y >> 2) ^ ((X0 + 1) & 15)) << 2) | (y & 3))] = v.y;
        tile[(X0 + 2) * 64 + ((((y >> 2) ^ ((X0 + 2) & 15)) << 2) | (y & 3))] = v.z;
        tile[(X0 + 3) * 64 + ((((y >> 2) ^ ((X0 + 3) & 15)) << 2) | (y & 3))] = v.w;
    }
    __syncthreads();
#pragma unroll
    for (int j = 0; j < 4; ++j) {
        int r = ty + 16 * j;
        float4 w = *(const float4*)&tile[r * 64 + ((tx ^ (r & 15)) << 2)];
        ((float4*)(out + (size_t)(bx * 64 + r) * NN + by * 64))[tx] = w;
    }
}

extern "C" void kernel_launch(void* const* d_in, const int* in_sizes, int n_in,
                              void* d_out, int out_size, void* d_ws, size_t ws_size,
                              hipStream_t stream) {
    const float* x      = (const float*)d_in[0];
    const float2* expkM = (const float2*)d_in[1];
    const float2* expkN = (const float2*)d_in[2];
    float* out = (float*)d_out;

    float2* tw4096 = (float2*)d_ws;                        // 16 KB
    float2* tw2048 = (float2*)((char*)d_ws + 16384);       // 16 KB
    float* A       = (float*)((char*)d_ws + 65536);        // 64 MB scratch

    tw_init_kernel<<<1, TT, 0, stream>>>(tw4096, tw2048);

    idct_rows_kernel<<<NN, TT, 0, stream>>>(x, expkN, tw4096, tw2048, A);
    {
        dim3 g(NN / 64, NN / 64), b(16, 16);
        transpose_kernel<<<g, b, 0, stream>>>(A, out);
    }
    idct_rows_kernel<<<NN, TT, 0, stream>>>(out, expkM, tw4096, tw2048, A);
    {
        dim3 g(NN / 64, NN / 64), b(16, 16);
        transpose_kernel<<<g, b, 0, stream>>>(A, out);
    }
}

// Round 3
// 203.716 us; speedup vs baseline: 1.2431x; 1.1137x over previous
//
#include <hip/hip_runtime.h>
#include <math.h>

// 2D IDCT 4096x4096.
// Pass 1 (columns): two-step global Stockham, 2048 = 32 x 64, coalesced over
//   the column index c.  colA: Z-build + 32-pt register FFT.  colB: 64-pt
//   register FFT + de-interleave, writes final column-IDCT to d_out.
// Pass 2 (rows): in-place LDS radix-8/8/8/4 Stockham per row on d_out.
// Z[k] = A[k]x[k] + B[k]x[4096-k] + C[k]x[2048+k] + D[k]x[2048-k] with
// precomputed complex coeffs (Makhoul half-size packing folded in).

#define TT 256

// ---- constexpr twiddle table: W64[j] = e^{+2*pi*i*j/64}, j=0..31 ----------
constexpr float W64R[32] = {
    1.0f, 0.995184726672197f, 0.980785280403230f, 0.956940335732209f,
    0.923879532511287f, 0.881921264348355f, 0.831469612302545f, 0.773010453362737f,
    0.707106781186548f, 0.634393284163645f, 0.555570233019602f, 0.471396736825998f,
    0.382683432365090f, 0.290284677254462f, 0.195090322016128f, 0.0980171403295606f,
    0.0f, -0.0980171403295606f, -0.195090322016128f, -0.290284677254462f,
    -0.382683432365090f, -0.471396736825998f, -0.555570233019602f, -0.634393284163645f,
    -0.707106781186548f, -0.773010453362737f, -0.831469612302545f, -0.881921264348355f,
    -0.923879532511287f, -0.956940335732209f, -0.980785280403230f, -0.995184726672197f};
constexpr float W64I[32] = {
    0.0f, 0.0980171403295606f, 0.195090322016128f, 0.290284677254462f,
    0.382683432365090f, 0.471396736825998f, 0.555570233019602f, 0.634393284163645f,
    0.707106781186548f, 0.773010453362737f, 0.831469612302545f, 0.881921264348355f,
    0.923879532511287f, 0.956940335732209f, 0.980785280403230f, 0.995184726672197f,
    1.0f, 0.995184726672197f, 0.980785280403230f, 0.956940335732209f,
    0.923879532511287f, 0.881921264348355f, 0.831469612302545f, 0.773010453362737f,
    0.707106781186548f, 0.634393284163645f, 0.555570233019602f, 0.471396736825998f,
    0.382683432365090f, 0.290284677254462f, 0.195090322016128f, 0.0980171403295606f};

__device__ __forceinline__ constexpr int brev(int x, int bits) {
    int r = 0;
    for (int i = 0; i < bits; ++i) { r = (r << 1) | (x & 1); x >>= 1; }
    return r;
}

// in-register DIF FFT (sign +), output bit-reversed: a[j] = z[brev(j)]
template <int NP>
__device__ __forceinline__ void fft_dif(float2* a) {
#pragma unroll
    for (int h = NP / 2; h >= 1; h >>= 1) {
#pragma unroll
        for (int b = 0; b < NP; b += 2 * h) {
#pragma unroll
            for (int k = 0; k < h; ++k) {
                float2 u = a[b + k], v = a[b + k + h];
                float dx = u.x - v.x, dy = u.y - v.y;
                a[b + k] = make_float2(u.x + v.x, u.y + v.y);
                float wr = W64R[k * (32 / h)], wi = W64I[k * (32 / h)];
                a[b + k + h] = make_float2(dx * wr - dy * wi, dx * wi + dy * wr);
            }
        }
    }
}

// ---- init: tw2048[k]=e^{2pi i k/2048}; coeff tables (double precision) ----
__global__ void tw_init_kernel(float2* __restrict__ tw2048,
                               float2* __restrict__ c1, float2* __restrict__ c2,
                               float2* __restrict__ c3, float2* __restrict__ c4) {
    int t = threadIdx.x;
    const double s = 0.5 / 4096.0;
    for (int i = 0; i < 8; ++i) {
        int k = t + 256 * i;
        double aw = M_PI * (double)k / 2048.0;          // 2*pi*k/4096
        double wr = cos(aw), wi = sin(aw);
        double a1 = M_PI * (double)k / 8192.0;          // pi*k/(2*4096)
        double e1r = cos(a1), e1i = sin(a1);
        double a2 = M_PI * (double)(k + 2048) / 8192.0;
        double e2r = cos(a2), e2i = sin(a2);
        double Ar = s * ((1.0 - wi) * e1r - wr * e1i);
        double Ai = s * ((1.0 - wi) * e1i + wr * e1r);
        double Br = (k == 0) ? 0.0 : Ai;
        double Bi = (k == 0) ? 0.0 : -Ar;
        double Cr = s * ((1.0 + wi) * e2r + wr * e2i);
        double Ci = s * ((1.0 + wi) * e2i - wr * e2r);
        c1[k] = make_float2((float)Ar, (float)Ai);
        c2[k] = make_float2((float)Br, (float)Bi);
        c3[k] = make_float2((float)Cr, (float)Ci);
        c4[k] = make_float2((float)Ci, (float)-Cr);
        double at = M_PI * (double)k / 1024.0;          // 2*pi*k/2048
        tw2048[k] = make_float2((float)cos(at), (float)sin(at));
    }
}

// ---- column pass A: Z-build + 32-pt FFT over k2; write T1[k1][n2][c] ------
__global__ __launch_bounds__(TT) void col_a_kernel(
    const float* __restrict__ x,
    const float2* __restrict__ c1, const float2* __restrict__ c2,
    const float2* __restrict__ c3, const float2* __restrict__ c4,
    const float2* __restrict__ tw2048, float2* __restrict__ T1) {
    int c = blockIdx.x * 64 + threadIdx.x;
    int k1 = blockIdx.y * 4 + threadIdx.y;
    float2 f[32];
#pragma unroll
    for (int k2 = 0; k2 < 32; ++k2) {
        int k = k1 + 64 * k2;
        float xa = x[(size_t)k * 4096 + c];
        float xb = x[(size_t)((4096 - k) & 4095) * 4096 + c];
        float xc = x[(size_t)(2048 + k) * 4096 + c];
        float xd = x[(size_t)(2048 - k) * 4096 + c];
        float2 A = c1[k], B = c2[k], C = c3[k], D = c4[k];
        f[k2].x = A.x * xa + B.x * xb + C.x * xc + D.x * xd;
        f[k2].y = A.y * xa + B.y * xb + C.y * xc + D.y * xd;
    }
    fft_dif<32>(f);
#pragma unroll
    for (int j = 0; j < 32; ++j) {
        int n2 = brev(j, 5);
        float2 w = tw2048[k1 * n2];
        float2 v = f[j];
        float2 o = make_float2(v.x * w.x - v.y * w.y, v.x * w.y + v.y * w.x);
        T1[(size_t)(k1 * 32 + n2) * 4096 + c] = o;
    }
}

// ---- column pass B: 64-pt FFT over k1; de-interleave to output rows -------
__global__ __launch_bounds__(TT) void col_b_kernel(
    const float2* __restrict__ T1, float* __restrict__ out) {
    int c = blockIdx.x * 64 + threadIdx.x;
    int n2 = blockIdx.y * 4 + threadIdx.y;
    float2 f[64];
#pragma unroll
    for (int k1 = 0; k1 < 64; ++k1)
        f[k1] = T1[(size_t)(k1 * 32 + n2) * 4096 + c];
    fft_dif<64>(f);
#pragma unroll
    for (int j = 0; j < 64; ++j) {
        int n1 = brev(j, 6);
        int m = 32 * n1 + n2;
        int r0 = (n1 < 32) ? (4 * m) : (8191 - 4 * m);
        int r1 = (n1 < 32) ? (4 * m + 2) : (8189 - 4 * m);
        out[(size_t)r0 * 4096 + c] = f[j].x;
        out[(size_t)r1 * 4096 + c] = f[j].y;
    }
}

// ---- radix-8 DFT (sign +) --------------------------------------------------
#define C_SQ2 0.70710678118654752440f
__device__ __forceinline__ void radix8(const float* ar, const float* ai,
                                       float* tr, float* ti) {
    float s04r = ar[0] + ar[4], s04i = ai[0] + ai[4];
    float d04r = ar[0] - ar[4], d04i = ai[0] - ai[4];
    float s26r = ar[2] + ar[6], s26i = ai[2] + ai[6];
    float d26r = ar[2] - ar[6], d26i = ai[2] - ai[6];
    float E0r = s04r + s26r, E0i = s04i + s26i;
    float E1r = d04r - d26i, E1i = d04i + d26r;
    float E2r = s04r - s26r, E2i = s04i - s26i;
    float E3r = d04r + d26i, E3i = d04i - d26r;
    float s15r = ar[1] + ar[5], s15i = ai[1] + ai[5];
    float d15r = ar[1] - ar[5], d15i = ai[1] - ai[5];
    float s37r = ar[3] + ar[7], s37i = ai[3] + ai[7];
    float d37r = ar[3] - ar[7], d37i = ai[3] - ai[7];
    float O0r = s15r + s37r, O0i = s15i + s37i;
    float O1r = d15r - d37i, O1i = d15i + d37r;
    float O2r = s15r - s37r, O2i = s15i - s37i;
    float O3r = d15r + d37i, O3i = d15i - d37r;
    float W1r = C_SQ2 * (O1r - O1i), W1i = C_SQ2 * (O1r + O1i);
    float W2r = -O2i, W2i = O2r;
    float W3r = -C_SQ2 * (O3r + O3i), W3i = C_SQ2 * (O3r - O3i);
    tr[0] = E0r + O0r; ti[0] = E0i + O0i;
    tr[4] = E0r - O0r; ti[4] = E0i - O0i;
    tr[1] = E1r + W1r; ti[1] = E1i + W1i;
    tr[5] = E1r - W1r; ti[5] = E1i - W1i;
    tr[2] = E2r + W2r; ti[2] = E2i + W2i;
    tr[6] = E2r - W2r; ti[6] = E2i - W2i;
    tr[3] = E3r + W3r; ti[3] = E3i + W3i;
    tr[7] = E3r - W3r; ti[7] = E3i - W3i;
}

// ---- row pass: in-place per-row IDCT, LDS Stockham radix 8/8/8/4 -----------
// b0 skew: i+(i>>5) (all accesses 2-way, free).  b1 skew: i+(i>>4).
__global__ __launch_bounds__(TT) void idct_rows_kernel(
    const float2* __restrict__ c1, const float2* __restrict__ c2,
    const float2* __restrict__ c3, const float2* __restrict__ c4,
    const float2* __restrict__ tw2048, float* __restrict__ io) {
    __shared__ float b0r[2112], b0i[2112], b1r[2176], b1i[2176];
    const int t = threadIdx.x;
    float* __restrict__ xr = io + (size_t)blockIdx.x * 4096;

    float zr[8], zi[8], tr[8], ti[8];
#pragma unroll
    for (int p = 0; p < 8; ++p) {
        int k = t + 256 * p;
        float xa = xr[k];
        float xb = xr[(4096 - k) & 4095];
        float xc = xr[2048 + k];
        float xd = xr[2048 - k];
        float2 A = c1[k], B = c2[k], C = c3[k], D = c4[k];
        zr[p] = A.x * xa + B.x * xb + C.x * xc + D.x * xd;
        zi[p] = A.y * xa + B.y * xb + C.y * xc + D.y * xd;
    }
    // stage A: m=1, j=t; write b0 at PHYS5(8t+q) = 8t+q+(t>>2)
    radix8(zr, zi, tr, ti);
    {
        int baseA = 8 * t + (t >> 2);
        b0r[baseA] = tr[0]; b0i[baseA] = ti[0];
#pragma unroll
        for (int q = 1; q < 8; ++q) {
            float2 w = tw2048[(t * q) & 2047];
            b0r[baseA + q] = w.x * tr[q] - w.y * ti[q];
            b0i[baseA + q] = w.x * ti[q] + w.y * tr[q];
        }
    }
    __syncthreads();
    // stage B: m=8; read b0 PHYS5(t)+264p, write b1 PHYS4(64j+8q+k)
    {
        float ar[8], ai[8];
        int rb = t + (t >> 5);
#pragma unroll
        for (int p = 0; p < 8; ++p) { ar[p] = b0r[rb + 264 * p]; ai[p] = b0i[rb + 264 * p]; }
        radix8(ar, ai, tr, ti);
        int j = t >> 3, k = t & 7, wj = 8 * j;
        int baseB = 68 * j + k;
        b1r[baseB] = tr[0]; b1i[baseB] = ti[0];
#pragma unroll
        for (int q = 1; q < 8; ++q) {
            int off = baseB + 8 * q + (q >> 1);
            float2 w = tw2048[(wj * q) & 2047];
            b1r[off] = w.x * tr[q] - w.y * ti[q];
            b1i[off] = w.x * ti[q] + w.y * tr[q];
        }
    }
    __syncthreads();
    // stage C: m=64; read b1 PHYS4(t)+272p, write b0 528j+66q+PHYS5(k)
    {
        float ar[8], ai[8];
        int rb = t + (t >> 4);
#pragma unroll
        for (int p = 0; p < 8; ++p) { ar[p] = b1r[rb + 272 * p]; ai[p] = b1i[rb + 272 * p]; }
        radix8(ar, ai, tr, ti);
        int j = t >> 6, wj = 64 * j, k = t & 63;
        int baseC = 528 * j + k + (k >> 5);
        b0r[baseC] = tr[0]; b0i[baseC] = ti[0];
#pragma unroll
        for (int q = 1; q < 8; ++q) {
            int off = baseC + 66 * q;
            float2 w = tw2048[(wj * q) & 2047];
            b0r[off] = w.x * tr[q] - w.y * ti[q];
            b0i[off] = w.x * ti[q] + w.y * tr[q];
        }
    }
    __syncthreads();
    // stage D: m=512, radix-4, tw=1; read b0 PHYS5(b)+528s, write b1 PHYS4(b)+544s
#pragma unroll
    for (int u = 0; u < 2; ++u) {
        int b = t + 256 * u;
        int rb = b + (b >> 5);
        int wb = b + (b >> 4);
        float a0r = b0r[rb], a0i = b0i[rb];
        float a1r = b0r[rb + 528], a1i = b0i[rb + 528];
        float a2r = b0r[rb + 1056], a2i = b0i[rb + 1056];
        float a3r = b0r[rb + 1584], a3i = b0i[rb + 1584];
        float s02r = a0r + a2r, s02i = a0i + a2i;
        float d02r = a0r - a2r, d02i = a0i - a2i;
        float s13r = a1r + a3r, s13i = a1i + a3i;
        float d13r = a1r - a3r, d13i = a1i - a3i;
        b1r[wb] = s02r + s13r;          b1i[wb] = s02i + s13i;
        b1r[wb + 544] = d02r - d13i;    b1i[wb + 544] = d02i + d13r;
        b1r[wb + 1088] = s02r - s13r;   b1i[wb + 1088] = s02i - s13i;
        b1r[wb + 1632] = d02r + d13i;   b1i[wb + 1632] = d02i - d13r;
    }
    __syncthreads();
    // de-interleave: out[2p]=v[p], out[2p+1]=v[4095-p]; v[2m]=Re, v[2m+1]=Im
#pragma unroll
    for (int i = 0; i < 16; ++i) {
        int q = t + 256 * i;
        int vidx = (q & 1) ? (4095 - ((q - 1) >> 1)) : (q >> 1);
        int l = vidx >> 1;
        int m_ = l + (l >> 4);
        float val = (vidx & 1) ? b1i[m_] : b1r[m_];
        xr[q] = val;
    }
}

extern "C" void kernel_launch(void* const* d_in, const int* in_sizes, int n_in,
                              void* d_out, int out_size, void* d_ws, size_t ws_size,
                              hipStream_t stream) {
    const float* x = (const float*)d_in[0];
    float* out = (float*)d_out;

    float2* tw2048 = (float2*)d_ws;
    float2* c1 = (float2*)((char*)d_ws + 1 * 16384);
    float2* c2 = (float2*)((char*)d_ws + 2 * 16384);
    float2* c3 = (float2*)((char*)d_ws + 3 * 16384);
    float2* c4 = (float2*)((char*)d_ws + 4 * 16384);
    float2* T1 = (float2*)((char*)d_ws + (1 << 20));   // 64 MB

    tw_init_kernel<<<1, TT, 0, stream>>>(tw2048, c1, c2, c3, c4);
    col_a_kernel<<<dim3(64, 16), dim3(64, 4), 0, stream>>>(x, c1, c2, c3, c4, tw2048, T1);
    col_b_kernel<<<dim3(64, 8), dim3(64, 4), 0, stream>>>(T1, out);
    idct_rows_kernel<<<4096, TT, 0, stream>>>(c1, c2, c3, c4, tw2048, out);
}

// Round 4
// 199.555 us; speedup vs baseline: 1.2690x; 1.0209x over previous
//
#include <hip/hip_runtime.h>
#include <math.h>

// 2D IDCT 4096x4096, all global access vectorized toward 16 B/lane.
// colA: Z-build + 32-pt register FFT, 2 columns/thread (float2 lockstep).
// colB: 64-pt register FFT + LDS-repacked float4 de-interleave stores.
// rows: in-place LDS Stockham radix-8/8/8/4 with float4 staged I/O.

#define TT 256

constexpr float W64R[32] = {
    1.0f, 0.995184726672197f, 0.980785280403230f, 0.956940335732209f,
    0.923879532511287f, 0.881921264348355f, 0.831469612302545f, 0.773010453362737f,
    0.707106781186548f, 0.634393284163645f, 0.555570233019602f, 0.471396736825998f,
    0.382683432365090f, 0.290284677254462f, 0.195090322016128f, 0.0980171403295606f,
    0.0f, -0.0980171403295606f, -0.195090322016128f, -0.290284677254462f,
    -0.382683432365090f, -0.471396736825998f, -0.555570233019602f, -0.634393284163645f,
    -0.707106781186548f, -0.773010453362737f, -0.831469612302545f, -0.881921264348355f,
    -0.923879532511287f, -0.956940335732209f, -0.980785280403230f, -0.995184726672197f};
constexpr float W64I[32] = {
    0.0f, 0.0980171403295606f, 0.195090322016128f, 0.290284677254462f,
    0.382683432365090f, 0.471396736825998f, 0.555570233019602f, 0.634393284163645f,
    0.707106781186548f, 0.773010453362737f, 0.831469612302545f, 0.881921264348355f,
    0.923879532511287f, 0.956940335732209f, 0.980785280403230f, 0.995184726672197f,
    1.0f, 0.995184726672197f, 0.980785280403230f, 0.956940335732209f,
    0.923879532511287f, 0.881921264348355f, 0.831469612302545f, 0.773010453362737f,
    0.707106781186548f, 0.634393284163645f, 0.555570233019602f, 0.471396736825998f,
    0.382683432365090f, 0.290284677254462f, 0.195090322016128f, 0.0980171403295606f};

__device__ __forceinline__ constexpr int brev(int x, int bits) {
    int r = 0;
    for (int i = 0; i < bits; ++i) { r = (r << 1) | (x & 1); x >>= 1; }
    return r;
}

__device__ __forceinline__ float vadd(float a, float b) { return a + b; }
__device__ __forceinline__ float vsub(float a, float b) { return a - b; }
__device__ __forceinline__ float vmul(float a, float s) { return a * s; }
__device__ __forceinline__ float2 vadd(float2 a, float2 b) { return make_float2(a.x + b.x, a.y + b.y); }
__device__ __forceinline__ float2 vsub(float2 a, float2 b) { return make_float2(a.x - b.x, a.y - b.y); }
__device__ __forceinline__ float2 vmul(float2 a, float s) { return make_float2(a.x * s, a.y * s); }

// in-register DIF FFT (sign +), output bit-reversed: re/im[j] = z[brev(j)]
template <int NP, typename V>
__device__ __forceinline__ void fft_dif(V* re, V* im) {
#pragma unroll
    for (int h = NP / 2; h >= 1; h >>= 1) {
#pragma unroll
        for (int b = 0; b < NP; b += 2 * h) {
#pragma unroll
            for (int k = 0; k < h; ++k) {
                V ur = re[b + k], ui = im[b + k];
                V vr = re[b + k + h], vi = im[b + k + h];
                V dr = vsub(ur, vr), di = vsub(ui, vi);
                re[b + k] = vadd(ur, vr);
                im[b + k] = vadd(ui, vi);
                float wr = W64R[k * (32 / h)], wi = W64I[k * (32 / h)];
                re[b + k + h] = vsub(vmul(dr, wr), vmul(di, wi));
                im[b + k + h] = vadd(vmul(dr, wi), vmul(di, wr));
            }
        }
    }
}

// ---- init: tw2048[k]=e^{2pi i k/2048}; Z coeff tables (double precision) --
__global__ void tw_init_kernel(float2* __restrict__ tw2048,
                               float2* __restrict__ ca, float2* __restrict__ cb,
                               float2* __restrict__ cc, float2* __restrict__ cd) {
    int k = blockIdx.x * TT + threadIdx.x;   // 8 blocks x 256 = 2048
    const double s = 0.5 / 4096.0;
    double aw = M_PI * (double)k / 2048.0;
    double wr = cos(aw), wi = sin(aw);
    double a1 = M_PI * (double)k / 8192.0;
    double e1r = cos(a1), e1i = sin(a1);
    double a2 = M_PI * (double)(k + 2048) / 8192.0;
    double e2r = cos(a2), e2i = sin(a2);
    double Ar = s * ((1.0 - wi) * e1r - wr * e1i);
    double Ai = s * ((1.0 - wi) * e1i + wr * e1r);
    double Br = (k == 0) ? 0.0 : Ai;
    double Bi = (k == 0) ? 0.0 : -Ar;
    double Cr = s * ((1.0 + wi) * e2r + wr * e2i);
    double Ci = s * ((1.0 + wi) * e2i - wr * e2r);
    ca[k] = make_float2((float)Ar, (float)Ai);
    cb[k] = make_float2((float)Br, (float)Bi);
    cc[k] = make_float2((float)Cr, (float)Ci);
    cd[k] = make_float2((float)Ci, (float)-Cr);
    double at = M_PI * (double)k / 1024.0;
    tw2048[k] = make_float2((float)cos(at), (float)sin(at));
}

// ---- column pass A: 2 columns per thread (float2), 32-pt FFT over k2 ------
__global__ __launch_bounds__(TT) void col_a_kernel(
    const float* __restrict__ x,
    const float2* __restrict__ ca, const float2* __restrict__ cb,
    const float2* __restrict__ cc, const float2* __restrict__ cd,
    const float2* __restrict__ tw2048, float2* __restrict__ T1) {
    int c2 = blockIdx.x * 64 + threadIdx.x;      // float2-column index
    int k1 = blockIdx.y * 4 + threadIdx.y;
    const float2* __restrict__ xv = (const float2*)x;   // rows of 2048 float2
    float2 fr[32], fi[32];
#pragma unroll
    for (int k2 = 0; k2 < 32; ++k2) {
        int k = k1 + 64 * k2;
        float2 xa = xv[(size_t)k * 2048 + c2];
        float2 xb = xv[(size_t)((4096 - k) & 4095) * 2048 + c2];
        float2 xc = xv[(size_t)(2048 + k) * 2048 + c2];
        float2 xd = xv[(size_t)(2048 - k) * 2048 + c2];
        float2 A = ca[k], B = cb[k], C = cc[k], D = cd[k];
        fr[k2] = make_float2(A.x * xa.x + B.x * xb.x + C.x * xc.x + D.x * xd.x,
                             A.x * xa.y + B.x * xb.y + C.x * xc.y + D.x * xd.y);
        fi[k2] = make_float2(A.y * xa.x + B.y * xb.x + C.y * xc.x + D.y * xd.x,
                             A.y * xa.y + B.y * xb.y + C.y * xc.y + D.y * xd.y);
    }
    fft_dif<32, float2>(fr, fi);
#pragma unroll
    for (int j = 0; j < 32; ++j) {
        int n2 = brev(j, 5);
        float2 w = tw2048[k1 * n2];
        float2 orr = vsub(vmul(fr[j], w.x), vmul(fi[j], w.y));
        float2 oii = vadd(vmul(fr[j], w.y), vmul(fi[j], w.x));
        float4 o = make_float4(orr.x, oii.x, orr.y, oii.y);
        *(float4*)&T1[(size_t)(k1 * 32 + n2) * 4096 + 2 * c2] = o;
    }
}

// ---- column pass B: 64-pt FFT over k1, LDS-repacked float4 stores ---------
__global__ __launch_bounds__(TT) void col_b_kernel(
    const float2* __restrict__ T1, float* __restrict__ out) {
    __shared__ float L[128 * 68];
    int tx = threadIdx.x, ty = threadIdx.y;
    int c = blockIdx.x * 64 + tx;
    int n2 = blockIdx.y * 4 + ty;
    float re[64], im[64];
#pragma unroll
    for (int k1 = 0; k1 < 64; ++k1) {
        float2 v = T1[(size_t)(k1 * 32 + n2) * 4096 + c];
        re[k1] = v.x; im[k1] = v.y;
    }
    fft_dif<64, float>(re, im);
    int tlin = ty * 64 + tx;
#pragma unroll
    for (int g = 0; g < 4; ++g) {
        if (ty == g) {
#pragma unroll
            for (int j = 0; j < 64; ++j) {
                int n1 = brev(j, 6);
                L[(2 * n1) * 68 + tx] = re[j];
                L[(2 * n1 + 1) * 68 + tx] = im[j];
            }
        }
        __syncthreads();
        int n2g = blockIdx.y * 4 + g;
#pragma unroll
        for (int u = 0; u < 8; ++u) {
            int idx = tlin + 256 * u;
            int slot = idx >> 4, xp = idx & 15;
            int n1 = slot >> 1;
            int m = 32 * n1 + n2g;
            int row = (n1 < 32) ? (4 * m + ((slot & 1) ? 2 : 0))
                                : (((slot & 1) ? 8189 : 8191) - 4 * m);
            float4 v = *(const float4*)&L[slot * 68 + 4 * xp];
            *(float4*)&out[(size_t)row * 4096 + blockIdx.x * 64 + 4 * xp] = v;
        }
        __syncthreads();
    }
}

// ---- radix-8 DFT (sign +) --------------------------------------------------
#define C_SQ2 0.70710678118654752440f
__device__ __forceinline__ void radix8(const float* ar, const float* ai,
                                       float* tr, float* ti) {
    float s04r = ar[0] + ar[4], s04i = ai[0] + ai[4];
    float d04r = ar[0] - ar[4], d04i = ai[0] - ai[4];
    float s26r = ar[2] + ar[6], s26i = ai[2] + ai[6];
    float d26r = ar[2] - ar[6], d26i = ai[2] - ai[6];
    float E0r = s04r + s26r, E0i = s04i + s26i;
    float E1r = d04r - d26i, E1i = d04i + d26r;
    float E2r = s04r - s26r, E2i = s04i - s26i;
    float E3r = d04r + d26i, E3i = d04i - d26r;
    float s15r = ar[1] + ar[5], s15i = ai[1] + ai[5];
    float d15r = ar[1] - ar[5], d15i = ai[1] - ai[5];
    float s37r = ar[3] + ar[7], s37i = ai[3] + ai[7];
    float d37r = ar[3] - ar[7], d37i = ai[3] - ai[7];
    float O0r = s15r + s37r, O0i = s15i + s37i;
    float O1r = d15r - d37i, O1i = d15i + d37r;
    float O2r = s15r - s37r, O2i = s15i - s37i;
    float O3r = d15r + d37i, O3i = d15i - d37r;
    float W1r = C_SQ2 * (O1r - O1i), W1i = C_SQ2 * (O1r + O1i);
    float W2r = -O2i, W2i = O2r;
    float W3r = -C_SQ2 * (O3r + O3i), W3i = C_SQ2 * (O3r - O3i);
    tr[0] = E0r + O0r; ti[0] = E0i + O0i;
    tr[4] = E0r - O0r; ti[4] = E0i - O0i;
    tr[1] = E1r + W1r; ti[1] = E1i + W1i;
    tr[5] = E1r - W1r; ti[5] = E1i - W1i;
    tr[2] = E2r + W2r; ti[2] = E2i + W2i;
    tr[6] = E2r - W2r; ti[6] = E2i - W2i;
    tr[3] = E3r + W3r; ti[3] = E3i + W3i;
    tr[7] = E3r - W3r; ti[7] = E3i - W3i;
}

// ---- row pass: in-place per-row IDCT, float4 staged I/O -------------------
// pool: b0r[2112] b0i[2112] b1r[2176] b1i[2176]; staging overlays b1 region.
__global__ __launch_bounds__(TT) void idct_rows_kernel(
    const float2* __restrict__ ca, const float2* __restrict__ cb,
    const float2* __restrict__ cc, const float2* __restrict__ cd,
    const float2* __restrict__ tw2048, float* __restrict__ io) {
    __shared__ float pool[8576];
    float* b0r = pool;
    float* b0i = pool + 2112;
    float* b1r = pool + 4224;
    float* b1i = pool + 6400;
    float* stg = pool + 4224;   // 4096 floats, overlays b1 (free until stage B)
    const int t = threadIdx.x;
    float* __restrict__ xr = io + (size_t)blockIdx.x * 4096;

    // stage the row via float4 loads
#pragma unroll
    for (int u = 0; u < 4; ++u) {
        int idx = t + 256 * u;
        float4 v = ((const float4*)xr)[idx];
        *(float4*)&stg[4 * idx] = v;
    }
    __syncthreads();

    float zr[8], zi[8], tr[8], ti[8];
#pragma unroll
    for (int p = 0; p < 8; ++p) {
        int k = t + 256 * p;
        float xa = stg[k];
        float xb = stg[(4096 - k) & 4095];
        float xc = stg[2048 + k];
        float xd = stg[2048 - k];
        float2 A = ca[k], B = cb[k], C = cc[k], D = cd[k];
        zr[p] = A.x * xa + B.x * xb + C.x * xc + D.x * xd;
        zi[p] = A.y * xa + B.y * xb + C.y * xc + D.y * xd;
    }
    // stage A: m=1, j=t; write b0 at 8t+q+(t>>2)
    radix8(zr, zi, tr, ti);
    {
        int baseA = 8 * t + (t >> 2);
        b0r[baseA] = tr[0]; b0i[baseA] = ti[0];
#pragma unroll
        for (int q = 1; q < 8; ++q) {
            float2 w = tw2048[(t * q) & 2047];
            b0r[baseA + q] = w.x * tr[q] - w.y * ti[q];
            b0i[baseA + q] = w.x * ti[q] + w.y * tr[q];
        }
    }
    __syncthreads();
    // stage B: m=8; read b0 (t+(t>>5))+264p, write b1 68j+k +8q+(q>>1)
    {
        float ar[8], ai[8];
        int rb = t + (t >> 5);
#pragma unroll
        for (int p = 0; p < 8; ++p) { ar[p] = b0r[rb + 264 * p]; ai[p] = b0i[rb + 264 * p]; }
        radix8(ar, ai, tr, ti);
        int j = t >> 3, k = t & 7, wj = 8 * j;
        int baseB = 68 * j + k;
        b1r[baseB] = tr[0]; b1i[baseB] = ti[0];
#pragma unroll
        for (int q = 1; q < 8; ++q) {
            int off = baseB + 8 * q + (q >> 1);
            float2 w = tw2048[(wj * q) & 2047];
            b1r[off] = w.x * tr[q] - w.y * ti[q];
            b1i[off] = w.x * ti[q] + w.y * tr[q];
        }
    }
    __syncthreads();
    // stage C: m=64; read b1 (t+(t>>4))+272p, write b0 528j+66q+k+(k>>5)
    {
        float ar[8], ai[8];
        int rb = t + (t >> 4);
#pragma unroll
        for (int p = 0; p < 8; ++p) { ar[p] = b1r[rb + 272 * p]; ai[p] = b1i[rb + 272 * p]; }
        radix8(ar, ai, tr, ti);
        int j = t >> 6, wj = 64 * j, k = t & 63;
        int baseC = 528 * j + k + (k >> 5);
        b0r[baseC] = tr[0]; b0i[baseC] = ti[0];
#pragma unroll
        for (int q = 1; q < 8; ++q) {
            int off = baseC + 66 * q;
            float2 w = tw2048[(wj * q) & 2047];
            b0r[off] = w.x * tr[q] - w.y * ti[q];
            b0i[off] = w.x * ti[q] + w.y * tr[q];
        }
    }
    __syncthreads();
    // stage D: m=512 radix-4, tw=1; read b0 (b+(b>>5))+528s, write b1 (b+(b>>4))+544s
#pragma unroll
    for (int u = 0; u < 2; ++u) {
        int b = t + 256 * u;
        int rb = b + (b >> 5);
        int wb = b + (b >> 4);
        float a0r = b0r[rb], a0i = b0i[rb];
        float a1r = b0r[rb + 528], a1i = b0i[rb + 528];
        float a2r = b0r[rb + 1056], a2i = b0i[rb + 1056];
        float a3r = b0r[rb + 1584], a3i = b0i[rb + 1584];
        float s02r = a0r + a2r, s02i = a0i + a2i;
        float d02r = a0r - a2r, d02i = a0i - a2i;
        float s13r = a1r + a3r, s13i = a1i + a3i;
        float d13r = a1r - a3r, d13i = a1i - a3i;
        b1r[wb] = s02r + s13r;          b1i[wb] = s02i + s13i;
        b1r[wb + 544] = d02r - d13i;    b1i[wb + 544] = d02i + d13r;
        b1r[wb + 1088] = s02r - s13r;   b1i[wb + 1088] = s02i - s13i;
        b1r[wb + 1632] = d02r + d13i;   b1i[wb + 1632] = d02i - d13r;
    }
    __syncthreads();
    // epilogue: out[4s..4s+3] = {Re z[s], Im z[2047-s], Im z[s], Re z[2047-s]}
#pragma unroll
    for (int i = 0; i < 4; ++i) {
        int s = t + 256 * i;
        int l2 = 2047 - s;
        int ms = s + (s >> 4);
        int ml = l2 + (l2 >> 4);
        float4 o = make_float4(b1r[ms], b1i[ml], b1i[ms], b1r[ml]);
        *(float4*)&xr[4 * s] = o;
    }
}

extern "C" void kernel_launch(void* const* d_in, const int* in_sizes, int n_in,
                              void* d_out, int out_size, void* d_ws, size_t ws_size,
                              hipStream_t stream) {
    const float* x = (const float*)d_in[0];
    float* out = (float*)d_out;

    float2* tw2048 = (float2*)d_ws;
    float2* ca = (float2*)((char*)d_ws + 1 * 16384);
    float2* cb = (float2*)((char*)d_ws + 2 * 16384);
    float2* cc = (float2*)((char*)d_ws + 3 * 16384);
    float2* cd = (float2*)((char*)d_ws + 4 * 16384);
    float2* T1 = (float2*)((char*)d_ws + (1 << 20));   // 64 MB

    tw_init_kernel<<<8, TT, 0, stream>>>(tw2048, ca, cb, cc, cd);
    col_a_kernel<<<dim3(32, 16), dim3(64, 4), 0, stream>>>(x, ca, cb, cc, cd, tw2048, T1);
    col_b_kernel<<<dim3(64, 8), dim3(64, 4), 0, stream>>>(T1, out);
    idct_rows_kernel<<<4096, TT, 0, stream>>>(ca, cb, cc, cd, tw2048, out);
}